// Round 1
// baseline (1563.451 us; speedup 1.0000x reference)
//
#include <hip/hip_runtime.h>

#define HH 512
#define WW 512
#define NPIX (HH*WW)
#define KK 16
#define BB 8
#define NB 8192   // lovasz error histogram buckets over e in [0,2]

__device__ __forceinline__ float fast_tanh(float x){
  x = fminf(fmaxf(x, -15.f), 15.f);
  float t = __expf(2.f*x);
  return (t-1.f)/(t+1.f);
}
__device__ __forceinline__ float fast_sigmoid(float x){
  x = fminf(fmaxf(x, -30.f), 30.f);
  return 1.f/(1.f+__expf(-x));
}

// ---------------- kernel 1: per-(b,k) mask sums + per-image bg seed sum ----
__global__ void __launch_bounds__(256) k_sums(
    const float* __restrict__ pred, const int* __restrict__ inst,
    const int* __restrict__ lab, float* __restrict__ sums /*[B][K][4]*/,
    float* __restrict__ seedbg /*[B]*/) {
  const int b = blockIdx.y;
  __shared__ float ls[KK*4 + 1];
  const int tid = threadIdx.x;
  for (int i = tid; i < KK*4 + 1; i += 256) ls[i] = 0.f;
  __syncthreads();
  const float inv = 1.f/511.f;
  const float* pb = pred + (size_t)b*4*NPIX;
  const int*   ib = inst + (size_t)b*NPIX;
  const int*   lb = lab  + (size_t)b*NPIX;
  float sbg = 0.f;
  const int base = blockIdx.x * 2048;
  for (int t = 0; t < 8; ++t) {
    int p = base + t*256 + tid;
    int id = ib[p];
    if (id >= 1 && id <= KK) {
      float xm = (float)(p & (WW-1)) * inv;
      float ym = (float)(p >> 9) * inv;
      int o = (id-1)*4;
      atomicAdd(&ls[o+0], 1.f);
      atomicAdd(&ls[o+1], xm);
      atomicAdd(&ls[o+2], ym);
      atomicAdd(&ls[o+3], pb[2*NPIX + p]);
    }
    if (lb[p] == 0) {
      float sd = fast_sigmoid(pb[3*NPIX + p]);
      sbg += sd*sd;
    }
  }
  atomicAdd(&ls[KK*4], sbg);
  __syncthreads();
  for (int i = tid; i < KK*4; i += 256)
    if (ls[i] != 0.f) atomicAdd(&sums[b*KK*4 + i], ls[i]);
  if (tid == 0) atomicAdd(&seedbg[b], ls[KK*4]);
}

// ---------------- kernel 2: derived per-instance scalars ------------------
__global__ void k_derive(const float* __restrict__ sums, float* __restrict__ der) {
  int i = threadIdx.x;
  if (i < BB*KK) {
    float cnt  = sums[i*4];
    float safe = fmaxf(cnt, 1.f);
    float cx = sums[i*4+1]/safe;
    float cy = sums[i*4+2]/safe;
    float s  = sums[i*4+3]/safe;
    der[i*4+0] = cx; der[i*4+1] = cy; der[i*4+2] = s;
    der[i*4+3] = __expf(10.f*s);
  }
}

// ---------------- kernel 3: dist per (pixel, instance) + hist + fg terms --
#define PPT 8
__global__ void __launch_bounds__(256) k_main(
    const float* __restrict__ pred, const int* __restrict__ inst,
    const float* __restrict__ sums, const float* __restrict__ der,
    unsigned long long* __restrict__ hist, float* __restrict__ acc /*[B][K][2]*/) {
  const int b = blockIdx.y;
  __shared__ float scx[KK], scy[KK], ss[KK], ssexp[KK];
  __shared__ int   sact[KK];
  __shared__ float svar[KK], ssee[KK];
  const int tid = threadIdx.x;
  if (tid < KK) {
    int seg = b*KK + tid;
    scx[tid]   = der[seg*4+0];
    scy[tid]   = der[seg*4+1];
    ss[tid]    = der[seg*4+2];
    ssexp[tid] = der[seg*4+3];
    sact[tid]  = (sums[seg*4] > 0.f);
    svar[tid] = 0.f; ssee[tid] = 0.f;
  }
  __syncthreads();
  const float inv = 1.f/511.f;
  const float* pb = pred + (size_t)b*4*NPIX;
  const int*   ib = inst + (size_t)b*NPIX;
  unsigned long long* hb = hist + (size_t)b*KK*NB;
  const int base = blockIdx.x * (256*PPT);
  for (int t = 0; t < PPT; ++t) {
    int p = base + t*256 + tid;
    float sex = fast_tanh(pb[p])        + (float)(p & (WW-1))*inv;
    float sey = fast_tanh(pb[NPIX + p]) + (float)(p >> 9)*inv;
    int id = ib[p];
    #pragma unroll
    for (int k = 0; k < KK; ++k) {
      if (!sact[k]) continue;
      float dx = sex - scx[k], dy = sey - scy[k];
      float d = __expf(-ssexp[k]*(dx*dx + dy*dy));
      bool fg = (id == k+1);
      float e = fg ? 2.f*(1.f - d) : 2.f*d;
      int bkt = (int)(e * (float)(NB/2));
      bkt = bkt < (NB-1) ? bkt : (NB-1);
      bkt = bkt > 0 ? bkt : 0;
      atomicAdd(&hb[(size_t)k*NB + bkt], fg ? 0x100000001ULL : 1ULL);
      if (fg) {
        float dsig = pb[2*NPIX + p] - ss[k];
        float dsee = fast_sigmoid(pb[3*NPIX + p]) - d;
        atomicAdd(&svar[k], dsig*dsig);
        atomicAdd(&ssee[k], dsee*dsee);
      }
    }
  }
  __syncthreads();
  if (tid < KK && sact[tid]) {
    if (svar[tid] != 0.f) atomicAdd(&acc[(b*KK+tid)*2+0], svar[tid]);
    if (ssee[tid] != 0.f) atomicAdd(&acc[(b*KK+tid)*2+1], ssee[tid]);
  }
}

// ---------------- kernel 4: lovasz via descending histogram scan ----------
__global__ void __launch_bounds__(64) k_lovasz(
    const unsigned long long* __restrict__ hist,
    const float* __restrict__ sums, float* __restrict__ instl) {
  const int seg = blockIdx.x;           // b*K + k
  const float gts = sums[seg*4];
  const int lane = threadIdx.x;         // 64 lanes, one wave
  if (gts <= 0.f) { if (lane == 0) instl[seg] = 0.f; return; }
  const unsigned long long* h = hist + (size_t)seg*NB;
  float carryN = 0.f, carryF = 0.f, lsum = 0.f;
  for (int it = 0; it < NB/64; ++it) {
    int j = it*64 + lane;
    int bkt = NB - 1 - j;               // descending error order
    unsigned long long c = h[bkt];
    float nb = (float)(unsigned int)(c & 0xffffffffu);
    float fb = (float)(unsigned int)(c >> 32);
    // inclusive wave scan of (nb, fb)
    float sn = nb, sf = fb;
    #pragma unroll
    for (int off = 1; off < 64; off <<= 1) {
      float tn = __shfl_up(sn, off);
      float tf = __shfl_up(sf, off);
      if (lane >= off) { sn += tn; sf += tf; }
    }
    float Nb = carryN + sn - nb;        // exclusive prefix (elements before bucket)
    float Fb = carryF + sf - fb;
    if (nb > 0.f) {
      float e  = ((float)bkt + 0.5f) * (2.0f/(float)NB);
      float j0 = 1.f - (gts - Fb) / (gts + Nb - Fb);
      float N1 = Nb + nb, F1 = Fb + fb;
      float j1 = 1.f - (gts - F1) / (gts + N1 - F1);
      lsum += e * (j1 - j0);
    }
    carryN += __shfl(sn, 63);
    carryF += __shfl(sf, 63);
  }
  #pragma unroll
  for (int off = 32; off; off >>= 1) lsum += __shfl_down(lsum, off);
  if (lane == 0) instl[seg] = lsum;
}

// ---------------- kernel 5: combine -----------------------------------------
__global__ void __launch_bounds__(64) k_final(
    const float* __restrict__ sums, const float* __restrict__ acc,
    const float* __restrict__ instl, const float* __restrict__ seedbg,
    float* __restrict__ out) {
  __shared__ float lb_[BB];
  int b = threadIdx.x;
  if (b < BB) {
    float obj = 0.f, il = 0.f, vr = 0.f, sl = 0.f;
    for (int k = 0; k < KK; ++k) {
      int seg = b*KK + k;
      float cnt = sums[seg*4];
      if (cnt > 0.f) {
        obj += 1.f;
        il  += instl[seg];
        vr  += acc[seg*2+0] / cnt;     // var / (N_SIGMA * safe), safe==cnt here
        sl  += acc[seg*2+1];           // FG_W == 1
      }
    }
    float safe_obj = fmaxf(obj, 1.f);
    float seed_total = (seedbg[b] + sl) / (float)NPIX;
    lb_[b] = il/safe_obj + 10.f*vr/safe_obj + seed_total;  // W_INST=1, W_VAR=10, W_SEED=1
  }
  __syncthreads();
  if (b == 0) {
    float t = 0.f;
    for (int i = 0; i < BB; ++i) t += lb_[i];
    out[0] = t / (float)BB;
  }
}

extern "C" void kernel_launch(void* const* d_in, const int* in_sizes, int n_in,
                              void* d_out, int out_size, void* d_ws, size_t ws_size,
                              hipStream_t stream) {
  const float* pred = (const float*)d_in[0];
  const int*   inst = (const int*)d_in[1];
  const int*   lab  = (const int*)d_in[2];
  float* out = (float*)d_out;

  // workspace layout (floats), histograms at byte offset 8192 (8B aligned)
  float* sums   = (float*)d_ws;            // 128*4
  float* seedbg = sums + 512;              // 8
  float* der    = seedbg + 8;              // 128*4
  float* acc    = der + 512;               // 128*2
  float* instl  = acc + 256;               // 128
  unsigned long long* hist = (unsigned long long*)((char*)d_ws + 8192);
  size_t zero_bytes = 8192 + (size_t)BB*KK*NB*sizeof(unsigned long long);

  hipMemsetAsync(d_ws, 0, zero_bytes, stream);

  k_sums  <<<dim3(NPIX/2048, BB), 256, 0, stream>>>(pred, inst, lab, sums, seedbg);
  k_derive<<<1, 128, 0, stream>>>(sums, der);
  k_main  <<<dim3(NPIX/(256*PPT), BB), 256, 0, stream>>>(pred, inst, sums, der, hist, acc);
  k_lovasz<<<BB*KK, 64, 0, stream>>>(hist, sums, instl);
  k_final <<<1, 64, 0, stream>>>(sums, acc, instl, seedbg, out);
}

// Round 2
// 292.282 us; speedup vs baseline: 5.3491x; 5.3491x over previous
//
#include <hip/hip_runtime.h>

#define HH 512
#define WW 512
#define NPIX (HH*WW)
#define KK 16
#define BB 8
#define NB 4096   // lovasz error histogram buckets over e in [0,2]
#define CH 2      // pixel chunks per (b,k)

__device__ __forceinline__ float fast_tanh(float x){
  x = fminf(fmaxf(x, -15.f), 15.f);
  float t = __expf(2.f*x);
  return (t-1.f)/(t+1.f);
}
__device__ __forceinline__ float fast_sigmoid(float x){
  x = fminf(fmaxf(x, -30.f), 30.f);
  return 1.f/(1.f+__expf(-x));
}

// ---------------- kernel 1: per-(b,k) mask sums + per-image bg seed sum ----
__global__ void __launch_bounds__(256) k_sums(
    const float* __restrict__ pred, const int* __restrict__ inst,
    const int* __restrict__ lab, float* __restrict__ sums /*[B][K][4]*/,
    float* __restrict__ seedbg /*[B]*/) {
  const int b = blockIdx.y;
  __shared__ float ls[KK*4 + 1];
  const int tid = threadIdx.x;
  for (int i = tid; i < KK*4 + 1; i += 256) ls[i] = 0.f;
  __syncthreads();
  const float inv = 1.f/511.f;
  const float* pb = pred + (size_t)b*4*NPIX;
  const int*   ib = inst + (size_t)b*NPIX;
  const int*   lb = lab  + (size_t)b*NPIX;
  float sbg = 0.f;
  const int base = blockIdx.x * 2048;
  for (int t = 0; t < 8; ++t) {
    int p = base + t*256 + tid;
    int id = ib[p];
    if (id >= 1 && id <= KK) {
      float xm = (float)(p & (WW-1)) * inv;
      float ym = (float)(p >> 9) * inv;
      int o = (id-1)*4;
      atomicAdd(&ls[o+0], 1.f);
      atomicAdd(&ls[o+1], xm);
      atomicAdd(&ls[o+2], ym);
      atomicAdd(&ls[o+3], pb[2*NPIX + p]);
    }
    if (lb[p] == 0) {
      float sd = fast_sigmoid(pb[3*NPIX + p]);
      sbg += sd*sd;
    }
  }
  atomicAdd(&ls[KK*4], sbg);
  __syncthreads();
  for (int i = tid; i < KK*4; i += 256)
    if (ls[i] != 0.f) atomicAdd(&sums[b*KK*4 + i], ls[i]);
  if (tid == 0) atomicAdd(&seedbg[b], ls[KK*4]);
}

// ---------------- kernel 2: derived per-instance scalars ------------------
__global__ void k_derive(const float* __restrict__ sums, float* __restrict__ der) {
  int i = threadIdx.x;
  if (i < BB*KK) {
    float cnt  = sums[i*4];
    float safe = fmaxf(cnt, 1.f);
    float cx = sums[i*4+1]/safe;
    float cy = sums[i*4+2]/safe;
    float s  = sums[i*4+3]/safe;
    der[i*4+0] = cx; der[i*4+1] = cy; der[i*4+2] = s;
    der[i*4+3] = __expf(10.f*s);
  }
}

// ---------------- kernel 3: per-(b,k,chunk) LDS histogram + fg terms ------
// grid: 256 blocks; b = bid&7 (XCD-affine: each XCD works one image, pred
// slices stay in its 4MB L2), sk = (bid>>3)>>1, ch = (bid>>3)&1.
__global__ void __launch_bounds__(256) k_hist(
    const float* __restrict__ pred, const int* __restrict__ inst,
    const float* __restrict__ sums, const float* __restrict__ der,
    unsigned long long* __restrict__ hist /*[seg][CH][NB]*/,
    float* __restrict__ acc /*[B][K][2]*/) {
  const int bid = blockIdx.x;
  const int b  = bid & 7;
  const int sk = (bid >> 3) >> 1;
  const int ch = (bid >> 3) & 1;
  const int seg = b*KK + sk;
  __shared__ unsigned long long lh[NB];
  __shared__ float red[2][4];
  const int tid = threadIdx.x;
  for (int i = tid; i < NB; i += 256) lh[i] = 0ULL;
  __syncthreads();

  float svar = 0.f, ssee = 0.f;
  const bool active = sums[seg*4] > 0.f;
  if (active) {
    const float cx = der[seg*4+0], cy = der[seg*4+1];
    const float s  = der[seg*4+2], sexp = der[seg*4+3];
    const float inv = 1.f/511.f;
    const float* pbx = pred + (size_t)b*4*NPIX;
    const float* pby = pbx + NPIX;
    const float* pbs = pbx + 2*NPIX;
    const float* pbd = pbx + 3*NPIX;
    const int*   ib  = inst + (size_t)b*NPIX;
    const int base = ch * (NPIX/CH);
    for (int it = 0; it < (NPIX/CH)/1024; ++it) {   // 128 iters x 1024 px
      const int p = base + it*1024 + tid*4;
      float4 px = *(const float4*)(pbx + p);
      float4 py = *(const float4*)(pby + p);
      int4   iv = *(const int4*)(ib + p);
      const float ym  = (float)(p >> 9) * inv;
      const float xm0 = (float)(p & (WW-1)) * inv;
      float vxa[4] = {px.x, px.y, px.z, px.w};
      float vya[4] = {py.x, py.y, py.z, py.w};
      int   ida[4] = {iv.x, iv.y, iv.z, iv.w};
      #pragma unroll
      for (int j = 0; j < 4; ++j) {
        float sex = fast_tanh(vxa[j]) + xm0 + (float)j*inv;
        float sey = fast_tanh(vya[j]) + ym;
        float dx = sex - cx, dy = sey - cy;
        float d = __expf(-sexp*(dx*dx + dy*dy));
        bool fg = (ida[j] == sk+1);
        float e = fg ? 2.f*(1.f - d) : 2.f*d;
        int bkt = (int)(e * (float)(NB/2));
        bkt = bkt < (NB-1) ? bkt : (NB-1);
        bkt = bkt > 0 ? bkt : 0;
        atomicAdd(&lh[bkt], fg ? 0x100000001ULL : 1ULL);
        if (fg) {
          float dsig = pbs[p+j] - s;
          float dsee = fast_sigmoid(pbd[p+j]) - d;
          svar += dsig*dsig;
          ssee += dsee*dsee;
        }
      }
    }
  }
  __syncthreads();
  // flush LDS hist -> private global region (plain coalesced stores)
  unsigned long long* gh = hist + ((size_t)seg*CH + ch)*NB;
  for (int i = tid; i < NB; i += 256) gh[i] = lh[i];
  // block-reduce fg accumulators -> 2 global atomics
  #pragma unroll
  for (int off = 32; off; off >>= 1) {
    svar += __shfl_down(svar, off);
    ssee += __shfl_down(ssee, off);
  }
  const int wid = tid >> 6;
  if ((tid & 63) == 0) { red[0][wid] = svar; red[1][wid] = ssee; }
  __syncthreads();
  if (tid == 0 && active) {
    float v = red[0][0]+red[0][1]+red[0][2]+red[0][3];
    float e = red[1][0]+red[1][1]+red[1][2]+red[1][3];
    if (v != 0.f) atomicAdd(&acc[seg*2+0], v);
    if (e != 0.f) atomicAdd(&acc[seg*2+1], e);
  }
}

// ---------------- kernel 4: lovasz via descending histogram scan ----------
__global__ void __launch_bounds__(64) k_lovasz(
    const unsigned long long* __restrict__ hist,
    const float* __restrict__ sums, float* __restrict__ instl) {
  const int seg = blockIdx.x;           // b*K + k
  const float gts = sums[seg*4];
  const int lane = threadIdx.x;         // 64 lanes, one wave
  if (gts <= 0.f) { if (lane == 0) instl[seg] = 0.f; return; }
  const unsigned long long* h = hist + (size_t)seg*CH*NB;
  float carryN = 0.f, carryF = 0.f, lsum = 0.f;
  for (int it = 0; it < NB/64; ++it) {
    int j = it*64 + lane;
    int bkt = NB - 1 - j;               // descending error order
    // sum CH packed partials (fields can't carry: counts < 2^19)
    unsigned long long c = h[bkt] + h[NB + bkt];
    float nb = (float)(unsigned int)(c & 0xffffffffu);
    float fb = (float)(unsigned int)(c >> 32);
    // inclusive wave scan of (nb, fb)
    float sn = nb, sf = fb;
    #pragma unroll
    for (int off = 1; off < 64; off <<= 1) {
      float tn = __shfl_up(sn, off);
      float tf = __shfl_up(sf, off);
      if (lane >= off) { sn += tn; sf += tf; }
    }
    float Nb = carryN + sn - nb;        // exclusive prefix (elements before bucket)
    float Fb = carryF + sf - fb;
    if (nb > 0.f) {
      float e  = ((float)bkt + 0.5f) * (2.0f/(float)NB);
      float j0 = 1.f - (gts - Fb) / (gts + Nb - Fb);
      float N1 = Nb + nb, F1 = Fb + fb;
      float j1 = 1.f - (gts - F1) / (gts + N1 - F1);
      lsum += e * (j1 - j0);
    }
    carryN += __shfl(sn, 63);
    carryF += __shfl(sf, 63);
  }
  #pragma unroll
  for (int off = 32; off; off >>= 1) lsum += __shfl_down(lsum, off);
  if (lane == 0) instl[seg] = lsum;
}

// ---------------- kernel 5: combine -----------------------------------------
__global__ void __launch_bounds__(64) k_final(
    const float* __restrict__ sums, const float* __restrict__ acc,
    const float* __restrict__ instl, const float* __restrict__ seedbg,
    float* __restrict__ out) {
  __shared__ float lb_[BB];
  int b = threadIdx.x;
  if (b < BB) {
    float obj = 0.f, il = 0.f, vr = 0.f, sl = 0.f;
    for (int k = 0; k < KK; ++k) {
      int seg = b*KK + k;
      float cnt = sums[seg*4];
      if (cnt > 0.f) {
        obj += 1.f;
        il  += instl[seg];
        vr  += acc[seg*2+0] / cnt;     // var / (N_SIGMA * safe), safe==cnt
        sl  += acc[seg*2+1];           // FG_W == 1
      }
    }
    float safe_obj = fmaxf(obj, 1.f);
    float seed_total = (seedbg[b] + sl) / (float)NPIX;
    lb_[b] = il/safe_obj + 10.f*vr/safe_obj + seed_total;  // W_INST=1, W_VAR=10, W_SEED=1
  }
  __syncthreads();
  if (b == 0) {
    float t = 0.f;
    for (int i = 0; i < BB; ++i) t += lb_[i];
    out[0] = t / (float)BB;
  }
}

extern "C" void kernel_launch(void* const* d_in, const int* in_sizes, int n_in,
                              void* d_out, int out_size, void* d_ws, size_t ws_size,
                              hipStream_t stream) {
  const float* pred = (const float*)d_in[0];
  const int*   inst = (const int*)d_in[1];
  const int*   lab  = (const int*)d_in[2];
  float* out = (float*)d_out;

  // workspace layout (floats), histograms at byte offset 8192 (8B aligned)
  float* sums   = (float*)d_ws;            // 128*4
  float* seedbg = sums + 512;              // 8
  float* der    = seedbg + 8;              // 128*4
  float* acc    = der + 512;               // 128*2
  float* instl  = acc + 256;               // 128
  unsigned long long* hist = (unsigned long long*)((char*)d_ws + 8192);
  // total ws use: 8192 + 128*CH*NB*8 = 8,396,800 B (same as proven-good)

  hipMemsetAsync(d_ws, 0, 8192, stream);   // hist fully overwritten by k_hist

  k_sums  <<<dim3(NPIX/2048, BB), 256, 0, stream>>>(pred, inst, lab, sums, seedbg);
  k_derive<<<1, 128, 0, stream>>>(sums, der);
  k_hist  <<<BB*KK*CH, 256, 0, stream>>>(pred, inst, sums, der, hist, acc);
  k_lovasz<<<BB*KK, 64, 0, stream>>>(hist, sums, instl);
  k_final <<<1, 64, 0, stream>>>(sums, acc, instl, seedbg, out);
}

// Round 3
// 165.130 us; speedup vs baseline: 9.4680x; 1.7700x over previous
//
#include <hip/hip_runtime.h>

#define HH 512
#define WW 512
#define NPIX (HH*WW)
#define KK 16
#define BB 8
#define NB 1024  // lovasz error histogram buckets over e in [0,2]
#define CH 8     // pixel chunks per (b,k)

__device__ __forceinline__ float fast_tanh(float x){
  x = fminf(fmaxf(x, -15.f), 15.f);
  float t = __expf(2.f*x);
  return (t-1.f)/(t+1.f);
}
__device__ __forceinline__ float fast_sigmoid(float x){
  x = fminf(fmaxf(x, -30.f), 30.f);
  return 1.f/(1.f+__expf(-x));
}

// ---------------- kernel 1: per-(b,k) mask sums + per-image bg seed sum ----
__global__ void __launch_bounds__(256) k_sums(
    const float* __restrict__ pred, const int* __restrict__ inst,
    const int* __restrict__ lab, float* __restrict__ sums /*[B][K][4]*/,
    float* __restrict__ seedbg /*[B]*/) {
  const int b = blockIdx.y;
  __shared__ float ls[KK*4 + 1];
  const int tid = threadIdx.x;
  for (int i = tid; i < KK*4 + 1; i += 256) ls[i] = 0.f;
  __syncthreads();
  const float inv = 1.f/511.f;
  const float* pb = pred + (size_t)b*4*NPIX;
  const int*   ib = inst + (size_t)b*NPIX;
  const int*   lb = lab  + (size_t)b*NPIX;
  float sbg = 0.f;
  const int base = blockIdx.x * 2048;
  for (int t = 0; t < 8; ++t) {
    int p = base + t*256 + tid;
    int id = ib[p];
    if (id >= 1 && id <= KK) {
      float xm = (float)(p & (WW-1)) * inv;
      float ym = (float)(p >> 9) * inv;
      int o = (id-1)*4;
      atomicAdd(&ls[o+0], 1.f);
      atomicAdd(&ls[o+1], xm);
      atomicAdd(&ls[o+2], ym);
      atomicAdd(&ls[o+3], pb[2*NPIX + p]);
    }
    if (lb[p] == 0) {
      float sd = fast_sigmoid(pb[3*NPIX + p]);
      sbg += sd*sd;
    }
  }
  atomicAdd(&ls[KK*4], sbg);
  __syncthreads();
  for (int i = tid; i < KK*4; i += 256)
    if (ls[i] != 0.f) atomicAdd(&sums[b*KK*4 + i], ls[i]);
  if (tid == 0) atomicAdd(&seedbg[b], ls[KK*4]);
}

// ---------------- kernel 2: derived per-instance scalars ------------------
__global__ void k_derive(const float* __restrict__ sums, float* __restrict__ der) {
  int i = threadIdx.x;
  if (i < BB*KK) {
    float cnt  = sums[i*4];
    float safe = fmaxf(cnt, 1.f);
    float cx = sums[i*4+1]/safe;
    float cy = sums[i*4+2]/safe;
    float s  = sums[i*4+3]/safe;
    der[i*4+0] = cx; der[i*4+1] = cy; der[i*4+2] = s;
    der[i*4+3] = __expf(10.f*s);
  }
}

// ---------------- kernel 3: per-(b,k,chunk) LDS histogram + fg terms ------
// grid: 1024 blocks; b = bid&7 (XCD-affine), sk = (bid>>3)&15, ch = bid>>7.
// 4 blocks/CU -> 16 waves/CU; LDS hist 8KB.
__global__ void __launch_bounds__(256) k_hist(
    const float* __restrict__ pred, const int* __restrict__ inst,
    const float* __restrict__ sums, const float* __restrict__ der,
    unsigned long long* __restrict__ hist /*[seg][CH][NB]*/,
    float* __restrict__ acc /*[B][K][2]*/) {
  const int bid = blockIdx.x;
  const int b  = bid & 7;
  const int sk = (bid >> 3) & 15;
  const int ch = bid >> 7;
  const int seg = b*KK + sk;
  __shared__ unsigned long long lh[NB];
  __shared__ float red[2][4];
  const int tid = threadIdx.x;
  for (int i = tid; i < NB; i += 256) lh[i] = 0ULL;
  __syncthreads();

  float svar = 0.f, ssee = 0.f;
  const bool active = sums[seg*4] > 0.f;
  if (active) {
    const float cx = der[seg*4+0], cy = der[seg*4+1];
    const float s  = der[seg*4+2], sexp = der[seg*4+3];
    const float inv = 1.f/511.f;
    const float* pbx = pred + (size_t)b*4*NPIX;
    const float* pby = pbx + NPIX;
    const float* pbs = pbx + 2*NPIX;
    const float* pbd = pbx + 3*NPIX;
    const int*   ib  = inst + (size_t)b*NPIX;
    const int base = ch * (NPIX/CH);
    for (int it = 0; it < (NPIX/CH)/1024; ++it) {   // 32 iters x 1024 px
      const int p = base + it*1024 + tid*4;
      float4 px = *(const float4*)(pbx + p);
      float4 py = *(const float4*)(pby + p);
      int4   iv = *(const int4*)(ib + p);
      const float ym  = (float)(p >> 9) * inv;
      const float xm0 = (float)(p & (WW-1)) * inv;
      float vxa[4] = {px.x, px.y, px.z, px.w};
      float vya[4] = {py.x, py.y, py.z, py.w};
      int   ida[4] = {iv.x, iv.y, iv.z, iv.w};
      #pragma unroll
      for (int j = 0; j < 4; ++j) {
        float sex = fast_tanh(vxa[j]) + xm0 + (float)j*inv;
        float sey = fast_tanh(vya[j]) + ym;
        float dx = sex - cx, dy = sey - cy;
        float d = __expf(-sexp*(dx*dx + dy*dy));
        bool fg = (ida[j] == sk+1);
        float e = fg ? 2.f*(1.f - d) : 2.f*d;
        int bkt = (int)(e * (float)(NB/2));
        bkt = bkt < (NB-1) ? bkt : (NB-1);
        bkt = bkt > 0 ? bkt : 0;
        atomicAdd(&lh[bkt], fg ? 0x100000001ULL : 1ULL);
        if (fg) {
          float dsig = pbs[p+j] - s;
          float dsee = fast_sigmoid(pbd[p+j]) - d;
          svar += dsig*dsig;
          ssee += dsee*dsee;
        }
      }
    }
  }
  __syncthreads();
  // flush LDS hist -> private global region (plain coalesced stores)
  unsigned long long* gh = hist + ((size_t)seg*CH + ch)*NB;
  for (int i = tid; i < NB; i += 256) gh[i] = lh[i];
  // block-reduce fg accumulators -> 2 global atomics
  #pragma unroll
  for (int off = 32; off; off >>= 1) {
    svar += __shfl_down(svar, off);
    ssee += __shfl_down(ssee, off);
  }
  const int wid = tid >> 6;
  if ((tid & 63) == 0) { red[0][wid] = svar; red[1][wid] = ssee; }
  __syncthreads();
  if (tid == 0 && active) {
    float v = red[0][0]+red[0][1]+red[0][2]+red[0][3];
    float e = red[1][0]+red[1][1]+red[1][2]+red[1][3];
    if (v != 0.f) atomicAdd(&acc[seg*2+0], v);
    if (e != 0.f) atomicAdd(&acc[seg*2+1], e);
  }
}

// ---------------- kernel 4: lovasz via descending histogram scan ----------
__global__ void __launch_bounds__(64) k_lovasz(
    const unsigned long long* __restrict__ hist,
    const float* __restrict__ sums, float* __restrict__ instl) {
  const int seg = blockIdx.x;           // b*K + k
  const float gts = sums[seg*4];
  const int lane = threadIdx.x;         // 64 lanes, one wave
  if (gts <= 0.f) { if (lane == 0) instl[seg] = 0.f; return; }
  const unsigned long long* h = hist + (size_t)seg*CH*NB;
  float carryN = 0.f, carryF = 0.f, lsum = 0.f;
  for (int it = 0; it < NB/64; ++it) {
    int j = it*64 + lane;
    int bkt = NB - 1 - j;               // descending error order
    // sum CH packed partials (fields can't carry: counts < 2^26)
    unsigned long long c = 0ULL;
    #pragma unroll
    for (int q = 0; q < CH; ++q) c += h[q*NB + bkt];
    float nb = (float)(unsigned int)(c & 0xffffffffu);
    float fb = (float)(unsigned int)(c >> 32);
    // inclusive wave scan of (nb, fb)
    float sn = nb, sf = fb;
    #pragma unroll
    for (int off = 1; off < 64; off <<= 1) {
      float tn = __shfl_up(sn, off);
      float tf = __shfl_up(sf, off);
      if (lane >= off) { sn += tn; sf += tf; }
    }
    float Nb = carryN + sn - nb;        // exclusive prefix (elements before bucket)
    float Fb = carryF + sf - fb;
    if (nb > 0.f) {
      float e  = ((float)bkt + 0.5f) * (2.0f/(float)NB);
      float j0 = 1.f - (gts - Fb) / (gts + Nb - Fb);
      float N1 = Nb + nb, F1 = Fb + fb;
      float j1 = 1.f - (gts - F1) / (gts + N1 - F1);
      lsum += e * (j1 - j0);
    }
    carryN += __shfl(sn, 63);
    carryF += __shfl(sf, 63);
  }
  #pragma unroll
  for (int off = 32; off; off >>= 1) lsum += __shfl_down(lsum, off);
  if (lane == 0) instl[seg] = lsum;
}

// ---------------- kernel 5: combine -----------------------------------------
__global__ void __launch_bounds__(64) k_final(
    const float* __restrict__ sums, const float* __restrict__ acc,
    const float* __restrict__ instl, const float* __restrict__ seedbg,
    float* __restrict__ out) {
  __shared__ float lb_[BB];
  int b = threadIdx.x;
  if (b < BB) {
    float obj = 0.f, il = 0.f, vr = 0.f, sl = 0.f;
    for (int k = 0; k < KK; ++k) {
      int seg = b*KK + k;
      float cnt = sums[seg*4];
      if (cnt > 0.f) {
        obj += 1.f;
        il  += instl[seg];
        vr  += acc[seg*2+0] / cnt;     // var / (N_SIGMA * safe), safe==cnt
        sl  += acc[seg*2+1];           // FG_W == 1
      }
    }
    float safe_obj = fmaxf(obj, 1.f);
    float seed_total = (seedbg[b] + sl) / (float)NPIX;
    lb_[b] = il/safe_obj + 10.f*vr/safe_obj + seed_total;  // W_INST=1, W_VAR=10, W_SEED=1
  }
  __syncthreads();
  if (b == 0) {
    float t = 0.f;
    for (int i = 0; i < BB; ++i) t += lb_[i];
    out[0] = t / (float)BB;
  }
}

extern "C" void kernel_launch(void* const* d_in, const int* in_sizes, int n_in,
                              void* d_out, int out_size, void* d_ws, size_t ws_size,
                              hipStream_t stream) {
  const float* pred = (const float*)d_in[0];
  const int*   inst = (const int*)d_in[1];
  const int*   lab  = (const int*)d_in[2];
  float* out = (float*)d_out;

  // workspace layout (floats), histograms at byte offset 8192 (8B aligned)
  float* sums   = (float*)d_ws;            // 128*4
  float* seedbg = sums + 512;              // 8
  float* der    = seedbg + 8;              // 128*4
  float* acc    = der + 512;               // 128*2
  float* instl  = acc + 256;               // 128
  unsigned long long* hist = (unsigned long long*)((char*)d_ws + 8192);
  // total ws use: 8192 + 128*CH*NB*8 = 8,396,800 B (same as proven-good)

  hipMemsetAsync(d_ws, 0, 8192, stream);   // hist fully overwritten by k_hist

  k_sums  <<<dim3(NPIX/2048, BB), 256, 0, stream>>>(pred, inst, lab, sums, seedbg);
  k_derive<<<1, 128, 0, stream>>>(sums, der);
  k_hist  <<<BB*KK*CH, 256, 0, stream>>>(pred, inst, sums, der, hist, acc);
  k_lovasz<<<BB*KK, 64, 0, stream>>>(hist, sums, instl);
  k_final <<<1, 64, 0, stream>>>(sums, acc, instl, seedbg, out);
}

// Round 5
// 119.541 us; speedup vs baseline: 13.0788x; 1.3814x over previous
//
#include <hip/hip_runtime.h>

#define HH 512
#define WW 512
#define NPIX (HH*WW)
#define KK 16
#define BB 8
#define NB 512   // lovasz error histogram buckets over e in [0,2]
#define CH 32    // pixel chunks per (b, kgroup)
#define KG 4     // instances per k_hist block

__device__ __forceinline__ float fast_rcp(float x){ return __builtin_amdgcn_rcpf(x); }
__device__ __forceinline__ float fast_tanh(float x){
  x = fminf(fmaxf(x, -15.f), 15.f);
  float t = __expf(2.f*x);
  return (t-1.f)*fast_rcp(t+1.f);
}
__device__ __forceinline__ float fast_sigmoid(float x){
  x = fminf(fmaxf(x, -30.f), 30.f);
  return fast_rcp(1.f+__expf(-x));
}

// ---------------- kernel 1: per-(b,k) mask sums + per-image bg seed sum ----
__global__ void __launch_bounds__(256) k_sums(
    const float* __restrict__ pred, const int* __restrict__ inst,
    const int* __restrict__ lab, float* __restrict__ sums /*[B][K][4]*/,
    float* __restrict__ seedbg /*[B]*/) {
  const int b = blockIdx.y;
  __shared__ float ls[KK*4 + 1];
  const int tid = threadIdx.x;
  for (int i = tid; i < KK*4 + 1; i += 256) ls[i] = 0.f;
  __syncthreads();
  const float inv = 1.f/511.f;
  const float* ps = pred + (size_t)b*4*NPIX + 2*NPIX;  // sigma channel
  const float* pd = ps + NPIX;                          // seed channel
  const int*   ib = inst + (size_t)b*NPIX;
  const int*   lb = lab  + (size_t)b*NPIX;
  float sbg = 0.f;
  const int base = blockIdx.x * 2048;
  for (int t = 0; t < 2; ++t) {
    int p = base + t*1024 + tid*4;
    int4   iv = *(const int4*)(ib + p);
    int4   lv = *(const int4*)(lb + p);
    float4 sv = *(const float4*)(ps + p);
    float4 dv = *(const float4*)(pd + p);
    float ym  = (float)(p >> 9) * inv;
    float xm0 = (float)(p & (WW-1)) * inv;
    int   ida[4] = {iv.x, iv.y, iv.z, iv.w};
    int   laa[4] = {lv.x, lv.y, lv.z, lv.w};
    float sga[4] = {sv.x, sv.y, sv.z, sv.w};
    float sda[4] = {dv.x, dv.y, dv.z, dv.w};
    #pragma unroll
    for (int j = 0; j < 4; ++j) {
      int id = ida[j];
      if (id >= 1) {
        int o = (id-1)*4;
        atomicAdd(&ls[o+0], 1.f);
        atomicAdd(&ls[o+1], xm0 + (float)j*inv);
        atomicAdd(&ls[o+2], ym);
        atomicAdd(&ls[o+3], sga[j]);
      }
      if (laa[j] == 0) { float sd = fast_sigmoid(sda[j]); sbg += sd*sd; }
    }
  }
  // wave-reduce sbg, then one LDS atomic per wave
  #pragma unroll
  for (int off = 32; off; off >>= 1) sbg += __shfl_down(sbg, off);
  if ((tid & 63) == 0) atomicAdd(&ls[KK*4], sbg);
  __syncthreads();
  for (int i = tid; i < KK*4; i += 256)
    if (ls[i] != 0.f) atomicAdd(&sums[b*KK*4 + i], ls[i]);
  if (tid == 0) atomicAdd(&seedbg[b], ls[KK*4]);
}

// ---------------- kernel 2: fg var/seed terms (masked pixels only) ---------
// grid 1024: b = bid&7 (XCD-affine), ch = bid>>3 (128 chunks x 2048 px)
__global__ void __launch_bounds__(256) k_var(
    const float* __restrict__ pred, const int* __restrict__ inst,
    const float* __restrict__ sums, float* __restrict__ acc /*[B][K][2]*/) {
  const int bid = blockIdx.x;
  const int b  = bid & 7;
  const int ch = bid >> 3;
  __shared__ float lkd[KK][4];   // cx, cy, s, sexp
  __shared__ float lacc[KK][2];
  const int tid = threadIdx.x;
  if (tid < KK) {
    const float* sm = sums + (b*KK + tid)*4;
    float safe = fmaxf(sm[0], 1.f);
    float s = sm[3]/safe;
    lkd[tid][0] = sm[1]/safe; lkd[tid][1] = sm[2]/safe;
    lkd[tid][2] = s;          lkd[tid][3] = __expf(10.f*s);
    lacc[tid][0] = 0.f; lacc[tid][1] = 0.f;
  }
  __syncthreads();
  const float inv = 1.f/511.f;
  const float* pbx = pred + (size_t)b*4*NPIX;
  const float* pby = pbx + NPIX;
  const float* pbs = pbx + 2*NPIX;
  const float* pbd = pbx + 3*NPIX;
  const int*   ib  = inst + (size_t)b*NPIX;
  const int base = ch*2048;
  for (int t = 0; t < 2; ++t) {
    int p = base + t*1024 + tid*4;
    int4   iv = *(const int4*)(ib + p);
    float4 px = *(const float4*)(pbx + p);
    float4 py = *(const float4*)(pby + p);
    float4 sv = *(const float4*)(pbs + p);
    float4 dv = *(const float4*)(pbd + p);
    float ym  = (float)(p >> 9) * inv;
    float xm0 = (float)(p & (WW-1)) * inv;
    int   ida[4] = {iv.x, iv.y, iv.z, iv.w};
    float pxa[4] = {px.x, px.y, px.z, px.w};
    float pya[4] = {py.x, py.y, py.z, py.w};
    float sga[4] = {sv.x, sv.y, sv.z, sv.w};
    float sda[4] = {dv.x, dv.y, dv.z, dv.w};
    #pragma unroll
    for (int j = 0; j < 4; ++j) {
      int id = ida[j];
      if (id >= 1) {
        int k = id - 1;
        float cx = lkd[k][0], cy = lkd[k][1], s = lkd[k][2], sexp = lkd[k][3];
        float sex = fast_tanh(pxa[j]) + xm0 + (float)j*inv;
        float sey = fast_tanh(pya[j]) + ym;
        float dx = sex - cx, dy = sey - cy;
        float d = __expf(-sexp*(dx*dx + dy*dy));
        float dsig = sga[j] - s;
        float dsee = fast_sigmoid(sda[j]) - d;
        atomicAdd(&lacc[k][0], dsig*dsig);
        atomicAdd(&lacc[k][1], dsee*dsee);
      }
    }
  }
  __syncthreads();
  if (tid < KK*2) {
    float v = lacc[tid>>1][tid&1];
    if (v != 0.f) atomicAdd(&acc[(b*KK + (tid>>1))*2 + (tid&1)], v);
  }
}

// ---------------- kernel 3: 4-instance LDS u32 histograms -----------------
// grid 1024: b = bid&7, kg = (bid>>3)&3, ch = bid>>5 (8192 px per chunk)
__global__ void __launch_bounds__(256) k_hist(
    const float* __restrict__ pred, const int* __restrict__ inst,
    const float* __restrict__ sums, unsigned int* __restrict__ hist) {
  const int bid = blockIdx.x;
  const int b  = bid & 7;
  const int kg = (bid >> 3) & 3;
  const int ch = bid >> 5;
  const int k0 = kg*KG;
  __shared__ unsigned int lh[KG][NB];
  __shared__ float sder[KG][4];   // cx, cy, sexp, act
  const int tid = threadIdx.x;
  if (tid < KG) {
    const float* sm = sums + (b*KK + k0 + tid)*4;
    float cnt = sm[0];
    float safe = fmaxf(cnt, 1.f);
    sder[tid][0] = sm[1]/safe;
    sder[tid][1] = sm[2]/safe;
    sder[tid][2] = __expf(10.f*(sm[3]/safe));
    sder[tid][3] = (cnt > 0.f) ? 1.f : 0.f;
  }
  for (int i = tid; i < KG*NB; i += 256) ((unsigned int*)lh)[i] = 0u;
  __syncthreads();
  const float cx0 = sder[0][0], cy0 = sder[0][1], se0 = sder[0][2];
  const float cx1 = sder[1][0], cy1 = sder[1][1], se1 = sder[1][2];
  const float cx2 = sder[2][0], cy2 = sder[2][1], se2 = sder[2][2];
  const float cx3 = sder[3][0], cy3 = sder[3][1], se3 = sder[3][2];
  const bool a0 = sder[0][3] > 0.f, a1 = sder[1][3] > 0.f;
  const bool a2 = sder[2][3] > 0.f, a3 = sder[3][3] > 0.f;
  const float inv = 1.f/511.f;
  const float* pbx = pred + (size_t)b*4*NPIX;
  const float* pby = pbx + NPIX;
  const int*   ib  = inst + (size_t)b*NPIX;
  const int base = ch * (NPIX/CH);
  for (int it = 0; it < (NPIX/CH)/1024; ++it) {   // 8 iters x 1024 px
    int p = base + it*1024 + tid*4;
    float4 px = *(const float4*)(pbx + p);
    float4 py = *(const float4*)(pby + p);
    int4   iv = *(const int4*)(ib + p);
    float ym  = (float)(p >> 9) * inv;
    float xm0 = (float)(p & (WW-1)) * inv;
    float pxa[4] = {px.x, px.y, px.z, px.w};
    float pya[4] = {py.x, py.y, py.z, py.w};
    int   ida[4] = {iv.x, iv.y, iv.z, iv.w};
    #pragma unroll
    for (int j = 0; j < 4; ++j) {
      float sex = fast_tanh(pxa[j]) + xm0 + (float)j*inv;
      float sey = fast_tanh(pya[j]) + ym;
      int id = ida[j];
      #define DOK(K, CX, CY, SE, ACT)                                \
        if (ACT) {                                                   \
          float dx = sex - CX, dy = sey - CY;                        \
          float d = __expf(-SE*(dx*dx + dy*dy));                     \
          bool fg = (id == k0 + K + 1);                              \
          float t2 = d + d;                                          \
          float e  = fg ? (2.f - t2) : t2;                           \
          int bkt = (int)(e * (float)(NB/2));                        \
          bkt = bkt < (NB-1) ? bkt : (NB-1);                         \
          bkt = bkt > 0 ? bkt : 0;                                   \
          atomicAdd(&lh[K][bkt], fg ? 0x10001u : 1u);                \
        }
      DOK(0, cx0, cy0, se0, a0)
      DOK(1, cx1, cy1, se1, a1)
      DOK(2, cx2, cy2, se2, a2)
      DOK(3, cx3, cy3, se3, a3)
      #undef DOK
    }
  }
  __syncthreads();
  #pragma unroll
  for (int k = 0; k < KG; ++k) {
    unsigned int* gh = hist + ((size_t)(b*KK + k0 + k)*CH + ch)*NB;
    for (int i = tid; i < NB; i += 256) gh[i] = lh[k][i];
  }
}

// ---------------- kernel 4: lovasz via descending histogram scan ----------
__global__ void __launch_bounds__(64) k_lovasz(
    const unsigned int* __restrict__ hist,
    const float* __restrict__ sums, float* __restrict__ instl) {
  const int seg = blockIdx.x;           // b*K + k
  const float gts = sums[seg*4];
  const int lane = threadIdx.x;         // one wave
  if (gts <= 0.f) { if (lane == 0) instl[seg] = 0.f; return; }
  const unsigned int* h = hist + (size_t)seg*CH*NB;
  float carryN = 0.f, carryF = 0.f, lsum = 0.f;
  for (int it = 0; it < NB/64; ++it) {
    int bkt = NB - 1 - (it*64 + lane);   // descending error order
    unsigned int nlo = 0, nhi = 0;
    #pragma unroll
    for (int q = 0; q < CH; ++q) {
      unsigned int c = h[q*NB + bkt];
      nlo += c & 0xffffu; nhi += c >> 16;
    }
    float nb = (float)nlo, fb = (float)nhi;
    float sn = nb, sf = fb;
    #pragma unroll
    for (int off = 1; off < 64; off <<= 1) {
      float tn = __shfl_up(sn, off);
      float tf = __shfl_up(sf, off);
      if (lane >= off) { sn += tn; sf += tf; }
    }
    float Nb = carryN + sn - nb;        // exclusive prefix
    float Fb = carryF + sf - fb;
    if (nlo) {
      float e  = ((float)bkt + 0.5f) * (2.0f/(float)NB);
      float j0 = 1.f - (gts - Fb) / (gts + Nb - Fb);
      float N1 = Nb + nb, F1 = Fb + fb;
      float j1 = 1.f - (gts - F1) / (gts + N1 - F1);
      lsum += e * (j1 - j0);
    }
    carryN += __shfl(sn, 63);
    carryF += __shfl(sf, 63);
  }
  #pragma unroll
  for (int off = 32; off; off >>= 1) lsum += __shfl_down(lsum, off);
  if (lane == 0) instl[seg] = lsum;
}

// ---------------- kernel 5: combine -----------------------------------------
__global__ void __launch_bounds__(64) k_final(
    const float* __restrict__ sums, const float* __restrict__ acc,
    const float* __restrict__ instl, const float* __restrict__ seedbg,
    float* __restrict__ out) {
  int lane = threadIdx.x;
  float myv = 0.f;
  if (lane < BB) {
    int b = lane;
    float obj = 0.f, il = 0.f, vr = 0.f, sl = 0.f;
    for (int k = 0; k < KK; ++k) {
      int seg = b*KK + k;
      float cnt = sums[seg*4];
      if (cnt > 0.f) {
        obj += 1.f;
        il  += instl[seg];
        vr  += acc[seg*2+0] / cnt;     // var/(N_SIGMA*safe), safe==cnt
        sl  += acc[seg*2+1];           // FG_W == 1
      }
    }
    float so = fmaxf(obj, 1.f);
    myv = il/so + 10.f*vr/so + (seedbg[b] + sl)/(float)NPIX;
  }
  #pragma unroll
  for (int off = 4; off; off >>= 1) myv += __shfl_down(myv, off);
  if (lane == 0) out[0] = myv * (1.f/(float)BB);
}

extern "C" void kernel_launch(void* const* d_in, const int* in_sizes, int n_in,
                              void* d_out, int out_size, void* d_ws, size_t ws_size,
                              hipStream_t stream) {
  const float* pred = (const float*)d_in[0];
  const int*   inst = (const int*)d_in[1];
  const int*   lab  = (const int*)d_in[2];
  float* out = (float*)d_out;

  // ws layout: scalars in first 8192 B; u32 hist partials after.
  float* sums   = (float*)d_ws;                         // 128*4 f32 @ 0
  float* seedbg = sums + 512;                           // 8 @ 2048
  float* acc    = seedbg + 8;                           // 256 @ 2080
  float* instl  = acc + 256;                            // 128 @ 3104
  unsigned int* hist = (unsigned int*)((char*)d_ws + 8192);
  // hist: 128 segs * CH * NB * 4B = 8,388,608 B -> total 8,396,800 (proven)

  hipMemsetAsync(d_ws, 0, 8192, stream);   // hist fully overwritten by k_hist

  k_sums  <<<dim3(NPIX/2048, BB), 256, 0, stream>>>(pred, inst, lab, sums, seedbg);
  k_var   <<<1024, 256, 0, stream>>>(pred, inst, sums, acc);
  k_hist  <<<BB*KG*CH, 256, 0, stream>>>(pred, inst, sums, hist);
  k_lovasz<<<BB*KK, 64, 0, stream>>>(hist, sums, instl);
  k_final <<<1, 64, 0, stream>>>(sums, acc, instl, seedbg, out);
}

// Round 6
// 119.521 us; speedup vs baseline: 13.0810x; 1.0002x over previous
//
#include <hip/hip_runtime.h>

#define HH 512
#define WW 512
#define NPIX (HH*WW)
#define KK 16
#define BB 8
#define NB 512   // lovasz error histogram buckets over e in [0,2]
#define CH 32    // pixel chunks per (b, kgroup) in k_hist
#define KG 4     // instances per k_hist block
#define SCH 64   // pixel chunks per image in k_sums / k_var (512 blocks)

__device__ __forceinline__ float fast_rcp(float x){ return __builtin_amdgcn_rcpf(x); }
__device__ __forceinline__ float fast_tanh(float x){
  x = fminf(fmaxf(x, -15.f), 15.f);
  float t = __expf(2.f*x);
  return (t-1.f)*fast_rcp(t+1.f);
}
__device__ __forceinline__ float fast_sigmoid(float x){
  x = fminf(fmaxf(x, -30.f), 30.f);
  return fast_rcp(1.f+__expf(-x));
}

// ---------------- kernel 1: per-(b,k) mask sums -> per-block partials ------
// grid 512: b = bid&7 (XCD-affine), ch = bid>>3; 4096 px/block.
// Plain stores to partial_s[bid][68] — no contended global atomics.
__global__ void __launch_bounds__(256) k_sums(
    const float* __restrict__ pred, const int* __restrict__ inst,
    const int* __restrict__ lab, float* __restrict__ partial_s) {
  const int bid = blockIdx.x;
  const int b  = bid & 7;
  const int ch = bid >> 3;
  __shared__ float ls[KK*4 + 1];
  const int tid = threadIdx.x;
  for (int i = tid; i < KK*4 + 1; i += 256) ls[i] = 0.f;
  __syncthreads();
  const float inv = 1.f/511.f;
  const float* ps = pred + (size_t)b*4*NPIX + 2*NPIX;  // sigma channel
  const float* pd = ps + NPIX;                          // seed channel
  const int*   ib = inst + (size_t)b*NPIX;
  const int*   lb = lab  + (size_t)b*NPIX;
  float sbg = 0.f;
  const int base = ch * 4096;
  for (int t = 0; t < 4; ++t) {
    int p = base + t*1024 + tid*4;
    int4   iv = *(const int4*)(ib + p);
    int4   lv = *(const int4*)(lb + p);
    float4 sv = *(const float4*)(ps + p);
    float4 dv = *(const float4*)(pd + p);
    float ym  = (float)(p >> 9) * inv;
    float xm0 = (float)(p & (WW-1)) * inv;
    int   ida[4] = {iv.x, iv.y, iv.z, iv.w};
    int   laa[4] = {lv.x, lv.y, lv.z, lv.w};
    float sga[4] = {sv.x, sv.y, sv.z, sv.w};
    float sda[4] = {dv.x, dv.y, dv.z, dv.w};
    #pragma unroll
    for (int j = 0; j < 4; ++j) {
      int id = ida[j];
      if (id >= 1) {
        int o = (id-1)*4;
        atomicAdd(&ls[o+0], 1.f);
        atomicAdd(&ls[o+1], xm0 + (float)j*inv);
        atomicAdd(&ls[o+2], ym);
        atomicAdd(&ls[o+3], sga[j]);
      }
      if (laa[j] == 0) { float sd = fast_sigmoid(sda[j]); sbg += sd*sd; }
    }
  }
  #pragma unroll
  for (int off = 32; off; off >>= 1) sbg += __shfl_down(sbg, off);
  if ((tid & 63) == 0) atomicAdd(&ls[KK*4], sbg);
  __syncthreads();
  float* po = partial_s + (size_t)bid*68;
  for (int i = tid; i < KK*4 + 1; i += 256) po[i] = ls[i];
}

// ---------------- kernel 2: reduce partials -> sums, seedbg, der ----------
// grid 8 (one per image) x 128 threads
__global__ void __launch_bounds__(128) k_reduce(
    const float* __restrict__ partial_s, float* __restrict__ sums,
    float* __restrict__ seedbg, float* __restrict__ der /*[B][K][8]*/) {
  const int b = blockIdx.x;
  const int t = threadIdx.x;
  __shared__ float lsum[KK*4 + 1];
  if (t < KK*4 + 1) {
    float a = 0.f;
    for (int ch = 0; ch < SCH; ++ch) a += partial_s[(size_t)(ch*8 + b)*68 + t];
    lsum[t] = a;
    if (t < KK*4) sums[b*KK*4 + t] = a;
    else seedbg[b] = a;
  }
  __syncthreads();
  if (t < KK) {
    float cnt  = lsum[t*4+0];
    float safe = fmaxf(cnt, 1.f);
    float cx = lsum[t*4+1]/safe;
    float cy = lsum[t*4+2]/safe;
    float s  = lsum[t*4+3]/safe;
    float* dd = der + (b*KK + t)*8;
    dd[0] = cx; dd[1] = cy; dd[2] = s;
    dd[3] = __expf(10.f*s);
    dd[4] = (cnt > 0.f) ? 1.f : 0.f;
    dd[5] = cnt;
  }
}

// ---------------- kernel 3: fg var/seed terms -> per-block partials -------
// grid 512: b = bid&7, ch = bid>>3; 4096 px/block.
__global__ void __launch_bounds__(256) k_var(
    const float* __restrict__ pred, const int* __restrict__ inst,
    const float* __restrict__ der, float* __restrict__ partial_v) {
  const int bid = blockIdx.x;
  const int b  = bid & 7;
  const int ch = bid >> 3;
  __shared__ float lkd[KK][4];   // cx, cy, s, sexp
  __shared__ float lacc[KK][2];
  const int tid = threadIdx.x;
  if (tid < KK) {
    const float* dd = der + (b*KK + tid)*8;
    lkd[tid][0] = dd[0]; lkd[tid][1] = dd[1];
    lkd[tid][2] = dd[2]; lkd[tid][3] = dd[3];
    lacc[tid][0] = 0.f; lacc[tid][1] = 0.f;
  }
  __syncthreads();
  const float inv = 1.f/511.f;
  const float* pbx = pred + (size_t)b*4*NPIX;
  const float* pby = pbx + NPIX;
  const float* pbs = pbx + 2*NPIX;
  const float* pbd = pbx + 3*NPIX;
  const int*   ib  = inst + (size_t)b*NPIX;
  const int base = ch * 4096;
  for (int t = 0; t < 4; ++t) {
    int p = base + t*1024 + tid*4;
    int4   iv = *(const int4*)(ib + p);
    float4 px = *(const float4*)(pbx + p);
    float4 py = *(const float4*)(pby + p);
    float4 sv = *(const float4*)(pbs + p);
    float4 dv = *(const float4*)(pbd + p);
    float ym  = (float)(p >> 9) * inv;
    float xm0 = (float)(p & (WW-1)) * inv;
    int   ida[4] = {iv.x, iv.y, iv.z, iv.w};
    float pxa[4] = {px.x, px.y, px.z, px.w};
    float pya[4] = {py.x, py.y, py.z, py.w};
    float sga[4] = {sv.x, sv.y, sv.z, sv.w};
    float sda[4] = {dv.x, dv.y, dv.z, dv.w};
    #pragma unroll
    for (int j = 0; j < 4; ++j) {
      int id = ida[j];
      if (id >= 1) {
        int k = id - 1;
        float cx = lkd[k][0], cy = lkd[k][1], s = lkd[k][2], sexp = lkd[k][3];
        float sex = fast_tanh(pxa[j]) + xm0 + (float)j*inv;
        float sey = fast_tanh(pya[j]) + ym;
        float dx = sex - cx, dy = sey - cy;
        float d = __expf(-sexp*(dx*dx + dy*dy));
        float dsig = sga[j] - s;
        float dsee = fast_sigmoid(sda[j]) - d;
        atomicAdd(&lacc[k][0], dsig*dsig);
        atomicAdd(&lacc[k][1], dsee*dsee);
      }
    }
  }
  __syncthreads();
  if (tid < KK*2) partial_v[(size_t)bid*32 + tid] = lacc[tid>>1][tid&1];
}

// ---------------- kernel 4: reduce var partials -> acc --------------------
__global__ void __launch_bounds__(256) k_vreduce(
    const float* __restrict__ partial_v, float* __restrict__ acc) {
  const int t = threadIdx.x;            // 256 = 8 images x 32 slots
  const int b = t >> 5, s = t & 31;
  float a = 0.f;
  for (int ch = 0; ch < SCH; ++ch) a += partial_v[(size_t)(ch*8 + b)*32 + s];
  acc[b*32 + s] = a;
}

// ---------------- kernel 5: 4-instance LDS u32 histograms -----------------
// grid 1024: b = bid&7, kg = (bid>>3)&3, ch = bid>>5 (8192 px per chunk)
__global__ void __launch_bounds__(256) k_hist(
    const float* __restrict__ pred, const int* __restrict__ inst,
    const float* __restrict__ der, unsigned int* __restrict__ hist) {
  const int bid = blockIdx.x;
  const int b  = bid & 7;
  const int kg = (bid >> 3) & 3;
  const int ch = bid >> 5;
  const int k0 = kg*KG;
  __shared__ unsigned int lh[KG][NB];
  __shared__ float sder[KG][4];   // cx, cy, sexp, act
  const int tid = threadIdx.x;
  if (tid < KG) {
    const float* dd = der + (b*KK + k0 + tid)*8;
    sder[tid][0] = dd[0];
    sder[tid][1] = dd[1];
    sder[tid][2] = dd[3];
    sder[tid][3] = dd[4];
  }
  for (int i = tid; i < KG*NB; i += 256) ((unsigned int*)lh)[i] = 0u;
  __syncthreads();
  const float cx0 = sder[0][0], cy0 = sder[0][1], se0 = sder[0][2];
  const float cx1 = sder[1][0], cy1 = sder[1][1], se1 = sder[1][2];
  const float cx2 = sder[2][0], cy2 = sder[2][1], se2 = sder[2][2];
  const float cx3 = sder[3][0], cy3 = sder[3][1], se3 = sder[3][2];
  const bool a0 = sder[0][3] > 0.f, a1 = sder[1][3] > 0.f;
  const bool a2 = sder[2][3] > 0.f, a3 = sder[3][3] > 0.f;
  const float inv = 1.f/511.f;
  const float* pbx = pred + (size_t)b*4*NPIX;
  const float* pby = pbx + NPIX;
  const int*   ib  = inst + (size_t)b*NPIX;
  const int base = ch * (NPIX/CH);
  for (int it = 0; it < (NPIX/CH)/1024; ++it) {   // 8 iters x 1024 px
    int p = base + it*1024 + tid*4;
    float4 px = *(const float4*)(pbx + p);
    float4 py = *(const float4*)(pby + p);
    int4   iv = *(const int4*)(ib + p);
    float ym  = (float)(p >> 9) * inv;
    float xm0 = (float)(p & (WW-1)) * inv;
    float pxa[4] = {px.x, px.y, px.z, px.w};
    float pya[4] = {py.x, py.y, py.z, py.w};
    int   ida[4] = {iv.x, iv.y, iv.z, iv.w};
    #pragma unroll
    for (int j = 0; j < 4; ++j) {
      float sex = fast_tanh(pxa[j]) + xm0 + (float)j*inv;
      float sey = fast_tanh(pya[j]) + ym;
      int id = ida[j];
      #define DOK(K, CX, CY, SE, ACT)                                \
        if (ACT) {                                                   \
          float dx = sex - CX, dy = sey - CY;                        \
          float d = __expf(-SE*(dx*dx + dy*dy));                     \
          bool fg = (id == k0 + K + 1);                              \
          float t2 = d + d;                                          \
          float e  = fg ? (2.f - t2) : t2;                           \
          int bkt = (int)(e * (float)(NB/2));                        \
          bkt = bkt < (NB-1) ? bkt : (NB-1);                         \
          bkt = bkt > 0 ? bkt : 0;                                   \
          atomicAdd(&lh[K][bkt], fg ? 0x10001u : 1u);                \
        }
      DOK(0, cx0, cy0, se0, a0)
      DOK(1, cx1, cy1, se1, a1)
      DOK(2, cx2, cy2, se2, a2)
      DOK(3, cx3, cy3, se3, a3)
      #undef DOK
    }
  }
  __syncthreads();
  #pragma unroll
  for (int k = 0; k < KG; ++k) {
    unsigned int* gh = hist + ((size_t)(b*KK + k0 + k)*CH + ch)*NB;
    for (int i = tid; i < NB; i += 256) gh[i] = lh[k][i];
  }
}

// ---------------- kernel 6: lovasz via descending histogram scan ----------
__global__ void __launch_bounds__(64) k_lovasz(
    const unsigned int* __restrict__ hist,
    const float* __restrict__ sums, float* __restrict__ instl) {
  const int seg = blockIdx.x;           // b*K + k
  const float gts = sums[seg*4];
  const int lane = threadIdx.x;         // one wave
  if (gts <= 0.f) { if (lane == 0) instl[seg] = 0.f; return; }
  const unsigned int* h = hist + (size_t)seg*CH*NB;
  float carryN = 0.f, carryF = 0.f, lsum = 0.f;
  for (int it = 0; it < NB/64; ++it) {
    int bkt = NB - 1 - (it*64 + lane);   // descending error order
    unsigned int nlo = 0, nhi = 0;
    #pragma unroll
    for (int q = 0; q < CH; ++q) {
      unsigned int c = h[q*NB + bkt];
      nlo += c & 0xffffu; nhi += c >> 16;
    }
    float nb = (float)nlo, fb = (float)nhi;
    float sn = nb, sf = fb;
    #pragma unroll
    for (int off = 1; off < 64; off <<= 1) {
      float tn = __shfl_up(sn, off);
      float tf = __shfl_up(sf, off);
      if (lane >= off) { sn += tn; sf += tf; }
    }
    float Nb = carryN + sn - nb;        // exclusive prefix
    float Fb = carryF + sf - fb;
    if (nlo) {
      float e  = ((float)bkt + 0.5f) * (2.0f/(float)NB);
      float j0 = 1.f - (gts - Fb) / (gts + Nb - Fb);
      float N1 = Nb + nb, F1 = Fb + fb;
      float j1 = 1.f - (gts - F1) / (gts + N1 - F1);
      lsum += e * (j1 - j0);
    }
    carryN += __shfl(sn, 63);
    carryF += __shfl(sf, 63);
  }
  #pragma unroll
  for (int off = 32; off; off >>= 1) lsum += __shfl_down(lsum, off);
  if (lane == 0) instl[seg] = lsum;
}

// ---------------- kernel 7: combine -----------------------------------------
__global__ void __launch_bounds__(64) k_final(
    const float* __restrict__ sums, const float* __restrict__ acc,
    const float* __restrict__ instl, const float* __restrict__ seedbg,
    float* __restrict__ out) {
  int lane = threadIdx.x;
  float myv = 0.f;
  if (lane < BB) {
    int b = lane;
    float obj = 0.f, il = 0.f, vr = 0.f, sl = 0.f;
    for (int k = 0; k < KK; ++k) {
      int seg = b*KK + k;
      float cnt = sums[seg*4];
      if (cnt > 0.f) {
        obj += 1.f;
        il  += instl[seg];
        vr  += acc[seg*2+0] / cnt;     // var/(N_SIGMA*safe), safe==cnt
        sl  += acc[seg*2+1];           // FG_W == 1
      }
    }
    float so = fmaxf(obj, 1.f);
    myv = il/so + 10.f*vr/so + (seedbg[b] + sl)/(float)NPIX;
  }
  #pragma unroll
  for (int off = 4; off; off >>= 1) myv += __shfl_down(myv, off);
  if (lane == 0) out[0] = myv * (1.f/(float)BB);
}

extern "C" void kernel_launch(void* const* d_in, const int* in_sizes, int n_in,
                              void* d_out, int out_size, void* d_ws, size_t ws_size,
                              hipStream_t stream) {
  const float* pred = (const float*)d_in[0];
  const int*   inst = (const int*)d_in[1];
  const int*   lab  = (const int*)d_in[2];
  float* out = (float*)d_out;

  // scalar region [0, 8192): all fully overwritten every call (no memset).
  float* sums   = (float*)d_ws;                          // 512 f32 @ 0
  float* seedbg = (float*)((char*)d_ws + 2048);          // 8 f32
  float* der    = (float*)((char*)d_ws + 2112);          // 128*8 f32 (4KB)
  float* acc    = (float*)((char*)d_ws + 6208);          // 256 f32
  float* instl  = (float*)((char*)d_ws + 7232);          // 128 f32
  // hist region [8192, 8192+8MB): partial_s / partial_v live here transiently
  // (fully consumed by k_reduce / k_vreduce BEFORE k_hist overwrites).
  float*        partial_s = (float*)((char*)d_ws + 8192);        // 512*68 f32
  float*        partial_v = (float*)((char*)d_ws + 8192);        // 512*32 f32
  unsigned int* hist      = (unsigned int*)((char*)d_ws + 8192); // 8MB
  // total ws use: 8192 + 8,388,608 = 8,396,800 B (unchanged, proven)

  k_sums   <<<BB*SCH, 256, 0, stream>>>(pred, inst, lab, partial_s);
  k_reduce <<<BB, 128, 0, stream>>>(partial_s, sums, seedbg, der);
  k_var    <<<BB*SCH, 256, 0, stream>>>(pred, inst, der, partial_v);
  k_vreduce<<<1, 256, 0, stream>>>(partial_v, acc);
  k_hist   <<<BB*KG*CH, 256, 0, stream>>>(pred, inst, der, hist);
  k_lovasz <<<BB*KK, 64, 0, stream>>>(hist, sums, instl);
  k_final  <<<1, 64, 0, stream>>>(sums, acc, instl, seedbg, out);
}

// Round 7
// 111.200 us; speedup vs baseline: 14.0598x; 1.0748x over previous
//
#include <hip/hip_runtime.h>

#define HH 512
#define WW 512
#define NPIX (HH*WW)
#define KK 16
#define BB 8
#define NB 448   // lovasz error histogram buckets over e in [0,2] (%64==0)
#define CH 32    // pixel chunks per (b, kgroup) in k_histvar
#define KG 4     // instances per k_histvar block
#define NSL (KK*4 + 1)   // 65 partial slots in k_sums

__device__ __forceinline__ float fast_rcp(float x){ return __builtin_amdgcn_rcpf(x); }
__device__ __forceinline__ float fast_tanh(float x){
  x = fminf(fmaxf(x, -15.f), 15.f);
  float t = __expf(2.f*x);
  return (t-1.f)*fast_rcp(t+1.f);
}
__device__ __forceinline__ float fast_sigmoid(float x){
  x = fminf(fmaxf(x, -30.f), 30.f);
  return fast_rcp(1.f+__expf(-x));
}

// ---------------- kernel 1: mask sums -> transposed per-block partials -----
// grid 2048: b = bid&7 (XCD-affine), ch = bid>>3 in [0,256); 1024 px/block.
// One load batch per thread (4 px) -> latency paid once, hidden by 32 waves/CU.
__global__ void __launch_bounds__(256) k_sums(
    const float* __restrict__ pred, const int* __restrict__ inst,
    const int* __restrict__ lab, float* __restrict__ partial_s /*[B][65][256]*/) {
  const int bid = blockIdx.x;
  const int b  = bid & 7;
  const int ch = bid >> 3;
  __shared__ float ls[NSL];
  const int tid = threadIdx.x;
  if (tid < NSL) ls[tid] = 0.f;
  __syncthreads();
  const float inv = 1.f/511.f;
  const float* ps = pred + (size_t)b*4*NPIX + 2*NPIX;  // sigma channel
  const float* pd = ps + NPIX;                          // seed channel
  const int*   ib = inst + (size_t)b*NPIX;
  const int*   lb = lab  + (size_t)b*NPIX;
  const int p = ch*1024 + tid*4;
  int4   iv = *(const int4*)(ib + p);
  int4   lv = *(const int4*)(lb + p);
  float4 sv = *(const float4*)(ps + p);
  float4 dv = *(const float4*)(pd + p);
  const float ym  = (float)(p >> 9) * inv;
  const float xm0 = (float)(p & (WW-1)) * inv;
  int   ida[4] = {iv.x, iv.y, iv.z, iv.w};
  int   laa[4] = {lv.x, lv.y, lv.z, lv.w};
  float sga[4] = {sv.x, sv.y, sv.z, sv.w};
  float sda[4] = {dv.x, dv.y, dv.z, dv.w};
  float sbg = 0.f;
  #pragma unroll
  for (int j = 0; j < 4; ++j) {
    int id = ida[j];
    if (id >= 1) {
      int o = (id-1)*4;
      atomicAdd(&ls[o+0], 1.f);
      atomicAdd(&ls[o+1], xm0 + (float)j*inv);
      atomicAdd(&ls[o+2], ym);
      atomicAdd(&ls[o+3], sga[j]);
    }
    if (laa[j] == 0) { float sd = fast_sigmoid(sda[j]); sbg += sd*sd; }
  }
  #pragma unroll
  for (int off = 32; off; off >>= 1) sbg += __shfl_down(sbg, off);
  if ((tid & 63) == 0) atomicAdd(&ls[KK*4], sbg);
  __syncthreads();
  if (tid < NSL) partial_s[((size_t)b*NSL + tid)*256 + ch] = ls[tid];
}

// ---------------- kernel 2: reduce partials -> sums, seedbg, der ----------
// grid 8 x 256. Wave w handles slots w, w+4, ...; lane sums 4 chunks coalesced.
__global__ void __launch_bounds__(256) k_reduce(
    const float* __restrict__ partial_s, float* __restrict__ sums,
    float* __restrict__ seedbg, float* __restrict__ der /*[B][K][8]*/) {
  const int b = blockIdx.x;
  const int tid = threadIdx.x;
  const int w = tid >> 6, l = tid & 63;
  __shared__ float lsum[NSL];
  #pragma unroll
  for (int i = 0; i < 17; ++i) {
    int s = w + 4*i;
    if (s < NSL) {
      const float* row = partial_s + ((size_t)b*NSL + s)*256;
      float a = row[l] + row[l+64] + row[l+128] + row[l+192];
      #pragma unroll
      for (int off = 32; off; off >>= 1) a += __shfl_down(a, off);
      if (l == 0) lsum[s] = a;
    }
  }
  __syncthreads();
  if (tid < KK*4) sums[b*KK*4 + tid] = lsum[tid];
  if (tid == KK*4) seedbg[b] = lsum[KK*4];
  if (tid < KK) {
    float cnt  = lsum[tid*4+0];
    float safe = fmaxf(cnt, 1.f);
    float cx = lsum[tid*4+1]/safe;
    float cy = lsum[tid*4+2]/safe;
    float s  = lsum[tid*4+3]/safe;
    float* dd = der + (b*KK + tid)*8;
    dd[0] = cx; dd[1] = cy; dd[2] = s;
    dd[3] = __expf(10.f*s);
    dd[4] = (cnt > 0.f) ? 1.f : 0.f;
    dd[5] = cnt;
  }
}

// ---------------- kernel 3: fused 4-instance histograms + fg var/seed -----
// grid 1024: b = bid&7, kg = (bid>>3)&3, ch = bid>>5 (8192 px per block)
__global__ void __launch_bounds__(256, 4) k_histvar(
    const float* __restrict__ pred, const int* __restrict__ inst,
    const float* __restrict__ der, unsigned int* __restrict__ hist,
    float* __restrict__ partial_v /*[B][K][CH][2]*/) {
  const int bid = blockIdx.x;
  const int b  = bid & 7;
  const int kg = (bid >> 3) & 3;
  const int ch = bid >> 5;
  const int k0 = kg*KG;
  __shared__ unsigned int lh[KG][NB];
  __shared__ float sder[KG][6];   // cx, cy, sexp, act, s
  __shared__ float red[8][4];
  const int tid = threadIdx.x;
  if (tid < KG) {
    const float* dd = der + (b*KK + k0 + tid)*8;
    sder[tid][0] = dd[0]; sder[tid][1] = dd[1];
    sder[tid][2] = dd[3]; sder[tid][3] = dd[4];
    sder[tid][4] = dd[2];
  }
  for (int i = tid; i < KG*NB; i += 256) ((unsigned int*)lh)[i] = 0u;
  __syncthreads();
  const float cx0 = sder[0][0], cy0 = sder[0][1], se0 = sder[0][2], sm0 = sder[0][4];
  const float cx1 = sder[1][0], cy1 = sder[1][1], se1 = sder[1][2], sm1 = sder[1][4];
  const float cx2 = sder[2][0], cy2 = sder[2][1], se2 = sder[2][2], sm2 = sder[2][4];
  const float cx3 = sder[3][0], cy3 = sder[3][1], se3 = sder[3][2], sm3 = sder[3][4];
  const bool a0 = sder[0][3] > 0.f, a1 = sder[1][3] > 0.f;
  const bool a2 = sder[2][3] > 0.f, a3 = sder[3][3] > 0.f;
  const float inv = 1.f/511.f;
  const float* pbx = pred + (size_t)b*4*NPIX;
  const float* pby = pbx + NPIX;
  const float* pbs = pbx + 2*NPIX;
  const float* pbd = pbx + 3*NPIX;
  const int*   ib  = inst + (size_t)b*NPIX;
  const int base = ch * (NPIX/CH);
  float sv0=0.f, sv1=0.f, sv2=0.f, sv3=0.f;   // var partials
  float sq0=0.f, sq1=0.f, sq2=0.f, sq3=0.f;   // seed partials
  #pragma unroll
  for (int it = 0; it < 8; ++it) {            // 8 x 1024 px
    const int p = base + it*1024 + tid*4;
    float4 px = *(const float4*)(pbx + p);
    float4 py = *(const float4*)(pby + p);
    int4   iv = *(const int4*)(ib + p);
    const float ym  = (float)(p >> 9) * inv;
    const float xm0 = (float)(p & (WW-1)) * inv;
    float pxa[4] = {px.x, px.y, px.z, px.w};
    float pya[4] = {py.x, py.y, py.z, py.w};
    int   ida[4] = {iv.x, iv.y, iv.z, iv.w};
    #pragma unroll
    for (int j = 0; j < 4; ++j) {
      float sex = fast_tanh(pxa[j]) + xm0 + (float)j*inv;
      float sey = fast_tanh(pya[j]) + ym;
      int id = ida[j];
      float down = 0.f;                       // d of pixel's own instance
      #define DOK(K, CX, CY, SE, ACT)                                \
        if (ACT) {                                                   \
          float dx = sex - CX, dy = sey - CY;                        \
          float d = __expf(-SE*(dx*dx + dy*dy));                     \
          bool fg = (id == k0 + K + 1);                              \
          float t2 = d + d;                                          \
          float e  = fg ? (2.f - t2) : t2;                           \
          int bkt = (int)(e * (float)(NB/2));                        \
          bkt = bkt < (NB-1) ? bkt : (NB-1);                         \
          bkt = bkt > 0 ? bkt : 0;                                   \
          atomicAdd(&lh[K][bkt], fg ? 0x10001u : 1u);                \
          down = fg ? d : down;                                      \
        }
      DOK(0, cx0, cy0, se0, a0)
      DOK(1, cx1, cy1, se1, a1)
      DOK(2, cx2, cy2, se2, a2)
      DOK(3, cx3, cy3, se3, a3)
      #undef DOK
      int kl = id - 1 - k0;
      if ((unsigned)kl < 4u) {                // own instance handled here
        float sg = pbs[p + j];
        float sd = pbd[p + j];
        float sm = (kl==0) ? sm0 : (kl==1) ? sm1 : (kl==2) ? sm2 : sm3;
        float dsig = sg - sm;
        float dsee = fast_sigmoid(sd) - down;
        float dsq = dsig*dsig, deq = dsee*dsee;
        if (kl == 0) { sv0 += dsq; sq0 += deq; }
        else if (kl == 1) { sv1 += dsq; sq1 += deq; }
        else if (kl == 2) { sv2 += dsq; sq2 += deq; }
        else { sv3 += dsq; sq3 += deq; }
      }
    }
  }
  __syncthreads();
  // flush LDS hist -> private global region (plain coalesced stores)
  #pragma unroll
  for (int k = 0; k < KG; ++k) {
    unsigned int* gh = hist + ((size_t)(b*KK + k0 + k)*CH + ch)*NB;
    for (int i = tid; i < NB; i += 256) gh[i] = lh[k][i];
  }
  // block-reduce the 8 fg accumulators -> plain stores to partial_v
  #pragma unroll
  for (int off = 32; off; off >>= 1) {
    sv0 += __shfl_down(sv0, off); sq0 += __shfl_down(sq0, off);
    sv1 += __shfl_down(sv1, off); sq1 += __shfl_down(sq1, off);
    sv2 += __shfl_down(sv2, off); sq2 += __shfl_down(sq2, off);
    sv3 += __shfl_down(sv3, off); sq3 += __shfl_down(sq3, off);
  }
  const int wid = tid >> 6;
  if ((tid & 63) == 0) {
    red[0][wid] = sv0; red[1][wid] = sq0; red[2][wid] = sv1; red[3][wid] = sq1;
    red[4][wid] = sv2; red[5][wid] = sq2; red[6][wid] = sv3; red[7][wid] = sq3;
  }
  __syncthreads();
  if (tid < 8) {
    int slot = tid >> 1, comp = tid & 1;     // red idx = slot*2+comp
    float v = red[tid][0] + red[tid][1] + red[tid][2] + red[tid][3];
    partial_v[(((size_t)b*KK + k0 + slot)*CH + ch)*2 + comp] = v;
  }
}

// ---------------- kernel 4: lovasz via descending histogram scan ----------
__global__ void __launch_bounds__(64) k_lovasz(
    const unsigned int* __restrict__ hist,
    const float* __restrict__ sums, float* __restrict__ instl) {
  const int seg = blockIdx.x;           // b*K + k
  const float gts = sums[seg*4];
  const int lane = threadIdx.x;         // one wave
  if (gts <= 0.f) { if (lane == 0) instl[seg] = 0.f; return; }
  const unsigned int* h = hist + (size_t)seg*CH*NB;
  float carryN = 0.f, carryF = 0.f, lsum = 0.f;
  for (int it = 0; it < NB/64; ++it) {
    int bkt = NB - 1 - (it*64 + lane);   // descending error order
    unsigned int nlo = 0, nhi = 0;
    #pragma unroll
    for (int q = 0; q < CH; ++q) {
      unsigned int c = h[q*NB + bkt];
      nlo += c & 0xffffu; nhi += c >> 16;
    }
    float nb = (float)nlo, fb = (float)nhi;
    float sn = nb, sf = fb;
    #pragma unroll
    for (int off = 1; off < 64; off <<= 1) {
      float tn = __shfl_up(sn, off);
      float tf = __shfl_up(sf, off);
      if (lane >= off) { sn += tn; sf += tf; }
    }
    float Nb = carryN + sn - nb;        // exclusive prefix
    float Fb = carryF + sf - fb;
    if (nlo) {
      float e  = ((float)bkt + 0.5f) * (2.0f/(float)NB);
      float j0 = 1.f - (gts - Fb) / (gts + Nb - Fb);
      float N1 = Nb + nb, F1 = Fb + fb;
      float j1 = 1.f - (gts - F1) / (gts + N1 - F1);
      lsum += e * (j1 - j0);
    }
    carryN += __shfl(sn, 63);
    carryF += __shfl(sf, 63);
  }
  #pragma unroll
  for (int off = 32; off; off >>= 1) lsum += __shfl_down(lsum, off);
  if (lane == 0) instl[seg] = lsum;
}

// ---------------- kernel 5: vreduce + combine ------------------------------
__global__ void __launch_bounds__(256) k_final(
    const float* __restrict__ partial_v, const float* __restrict__ sums,
    const float* __restrict__ instl, const float* __restrict__ seedbg,
    float* __restrict__ out) {
  __shared__ float vsum[256];           // [b][k][comp] reduced over ch
  const int tid = threadIdx.x;
  {
    const int b = tid >> 5, k = (tid & 31) >> 1, comp = tid & 1;
    const float* pv = partial_v + (((size_t)b*KK + k)*CH)*2 + comp;
    float a = 0.f;
    #pragma unroll
    for (int ch = 0; ch < CH; ++ch) a += pv[ch*2];
    vsum[tid] = a;
  }
  __syncthreads();
  float myv = 0.f;
  if (tid < BB) {
    int b = tid;
    float obj = 0.f, il = 0.f, vr = 0.f, sl = 0.f;
    for (int k = 0; k < KK; ++k) {
      float cnt = sums[(b*KK + k)*4];
      if (cnt > 0.f) {
        obj += 1.f;
        il  += instl[b*KK + k];
        vr  += vsum[b*32 + k*2 + 0] / cnt;   // var/(N_SIGMA*safe), safe==cnt
        sl  += vsum[b*32 + k*2 + 1];         // FG_W == 1
      }
    }
    float so = fmaxf(obj, 1.f);
    myv = il/so + 10.f*vr/so + (seedbg[b] + sl)/(float)NPIX;
  }
  #pragma unroll
  for (int off = 4; off; off >>= 1) myv += __shfl_down(myv, off);
  if (tid == 0) out[0] = myv * (1.f/(float)BB);
}

extern "C" void kernel_launch(void* const* d_in, const int* in_sizes, int n_in,
                              void* d_out, int out_size, void* d_ws, size_t ws_size,
                              hipStream_t stream) {
  const float* pred = (const float*)d_in[0];
  const int*   inst = (const int*)d_in[1];
  const int*   lab  = (const int*)d_in[2];
  float* out = (float*)d_out;

  // scalar region [0, 8192): all fully overwritten every call (no memset).
  float* sums   = (float*)d_ws;                          // 512 f32 @ 0
  float* seedbg = (float*)((char*)d_ws + 2048);          // 8 f32
  float* der    = (float*)((char*)d_ws + 2112);          // 128*8 f32
  float* instl  = (float*)((char*)d_ws + 6208);          // 128 f32
  // [8192, +7,340,032): hist (128 segs * 32 ch * 448 * 4B)
  unsigned int* hist = (unsigned int*)((char*)d_ws + 8192);
  // disjoint tails (all within proven 8,396,800 B budget):
  float* partial_v = (float*)((char*)d_ws + 7348224);    // 8*16*32*2 f32 (32KB)
  float* partial_s = (float*)((char*)d_ws + 7380992);    // 8*65*256 f32 (520KB)

  k_sums   <<<BB*256, 256, 0, stream>>>(pred, inst, lab, partial_s);
  k_reduce <<<BB, 256, 0, stream>>>(partial_s, sums, seedbg, der);
  k_histvar<<<BB*KG*CH, 256, 0, stream>>>(pred, inst, der, hist, partial_v);
  k_lovasz <<<BB*KK, 64, 0, stream>>>(hist, sums, instl);
  k_final  <<<1, 256, 0, stream>>>(partial_v, sums, instl, seedbg, out);
}